// Round 2
// baseline (494.637 us; speedup 1.0000x reference)
//
#include <hip/hip_runtime.h>
#include <hip/hip_bf16.h>
#include <math.h>

#define Bn   4
#define Hh   56
#define Wn   56
#define Cn   256
#define NHn  8
#define HDn  32
#define Nn   3136
#define LLn  9
#define PLn  196
#define PWn  14
#define KTABn 2048

// ---------------------------------------------------------------------------
// Generic tiled GEMM: C[M,Nc] = A[M,K] @ W[Nc,K]^T + bias ; EPI: 0=none 1=gelu
// 64x64 tile, 256 threads, 4x4 per thread, K staged in 16-chunks via LDS.
// All fp32.
// ---------------------------------------------------------------------------
template <int EPI>
__launch_bounds__(256)
__global__ void gemm_k(const float* __restrict__ A, const float* __restrict__ W,
                       const float* __restrict__ bias, float* __restrict__ Co,
                       int Mr, int Nc, int K)
{
  __shared__ __align__(16) float As[16][64];
  __shared__ __align__(16) float Ws[16][64];
  const int t  = threadIdx.x;
  const int m0 = blockIdx.y * 64, n0 = blockIdx.x * 64;
  const int lm = t >> 2, lk = (t & 3) << 2;
  const int tx = t & 15, ty = t >> 4;
  float acc[4][4] = {};
  int arow = m0 + lm; if (arow >= Mr) arow = Mr - 1;
  const int wrow = n0 + lm;
  for (int k0 = 0; k0 < K; k0 += 16) {
    float4 av = *(const float4*)(A + (size_t)arow * K + k0 + lk);
    As[lk+0][lm] = av.x; As[lk+1][lm] = av.y; As[lk+2][lm] = av.z; As[lk+3][lm] = av.w;
    float4 wv = *(const float4*)(W + (size_t)wrow * K + k0 + lk);
    Ws[lk+0][lm] = wv.x; Ws[lk+1][lm] = wv.y; Ws[lk+2][lm] = wv.z; Ws[lk+3][lm] = wv.w;
    __syncthreads();
    #pragma unroll
    for (int k = 0; k < 16; ++k) {
      float4 a = *(const float4*)&As[k][ty << 2];
      float4 w = *(const float4*)&Ws[k][tx << 2];
      acc[0][0] += a.x*w.x; acc[0][1] += a.x*w.y; acc[0][2] += a.x*w.z; acc[0][3] += a.x*w.w;
      acc[1][0] += a.y*w.x; acc[1][1] += a.y*w.y; acc[1][2] += a.y*w.z; acc[1][3] += a.y*w.w;
      acc[2][0] += a.z*w.x; acc[2][1] += a.z*w.y; acc[2][2] += a.z*w.z; acc[2][3] += a.z*w.w;
      acc[3][0] += a.w*w.x; acc[3][1] += a.w*w.y; acc[3][2] += a.w*w.z; acc[3][3] += a.w*w.w;
    }
    __syncthreads();
  }
  #pragma unroll
  for (int i = 0; i < 4; ++i) {
    const int row = m0 + (ty << 2) + i;
    if (row >= Mr) continue;
    #pragma unroll
    for (int j = 0; j < 4; ++j) {
      const int col = n0 + (tx << 2) + j;
      float v = acc[i][j] + bias[col];
      if constexpr (EPI == 1) v = 0.5f * v * (1.0f + erff(v * 0.70710678118654752f));
      Co[(size_t)row * Nc + col] = v;
    }
  }
}

// ---------------------------------------------------------------------------
// Per-head L2 norm of q (in place) + q_scaled; per-head L2 norm of k (in place)
// one block per row (b*N+n), 256 threads = 256 channels
// ---------------------------------------------------------------------------
__launch_bounds__(256)
__global__ void norm_qk(float* __restrict__ q, float* __restrict__ qs, float* __restrict__ kv,
                        const float* __restrict__ sls, const float* __restrict__ qe,
                        const float* __restrict__ temp)
{
  const int row = blockIdx.x;
  const int c = threadIdx.x;
  const int h = c >> 5;
  const int n = row % Nn;
  float qv = q[(size_t)row * Cn + c];
  float ss = qv * qv;
  #pragma unroll
  for (int m = 16; m >= 1; m >>= 1) ss += __shfl_xor(ss, m);   // 32-lane group (head)
  float qn = qv / fmaxf(sqrtf(ss), 1e-12f);
  q[(size_t)row * Cn + c] = qn;
  float spt = log1pf(expf(temp[h]));
  qs[(size_t)row * Cn + c] = (qn + qe[c]) * spt * sls[n];
  float kval = kv[(size_t)row * 512 + c];
  float ks = kval * kval;
  #pragma unroll
  for (int m = 16; m >= 1; m >>= 1) ks += __shfl_xor(ks, m);
  kv[(size_t)row * 512 + c] = kval / fmaxf(sqrtf(ks), 1e-12f);
}

// ---------------------------------------------------------------------------
// 4x4 average pool of x_sr (already gelu'd) + LayerNorm over C
// one block per (b, pool cell), 256 threads = channels
// ---------------------------------------------------------------------------
__launch_bounds__(256)
__global__ void pool_ln_k(const float* __restrict__ xsr, float* __restrict__ pln,
                          const float* __restrict__ g, const float* __restrict__ bb)
{
  const int blk = blockIdx.x;
  const int b = blk / PLn, pc = blk % PLn;
  const int pi = pc / PWn, pj = pc % PWn;
  const int c = threadIdx.x;
  float s = 0.f;
  #pragma unroll
  for (int r = 0; r < 4; ++r)
    #pragma unroll
    for (int cc = 0; cc < 4; ++cc) {
      const int n = (pi*4 + r) * Wn + pj*4 + cc;
      s += xsr[((size_t)b * Nn + n) * Cn + c];
    }
  s *= (1.f/16.f);
  float sum = s, sq = s*s;
  #pragma unroll
  for (int m = 32; m >= 1; m >>= 1) { sum += __shfl_xor(sum, m); sq += __shfl_xor(sq, m); }
  __shared__ float sm[8];
  const int lane = c & 63, wid = c >> 6;
  if (lane == 0) { sm[wid] = sum; sm[4+wid] = sq; }
  __syncthreads();
  const float tot  = sm[0]+sm[1]+sm[2]+sm[3];
  const float totq = sm[4]+sm[5]+sm[6]+sm[7];
  const float mu  = tot * (1.f/256.f);
  const float var = totq * (1.f/256.f) - mu*mu;
  pln[(size_t)blk * Cn + c] = (s - mu) / sqrtf(var + 1e-5f) * g[c] + bb[c];
}

// ---------------------------------------------------------------------------
// split kvp -> k_pool (L2-normed per head) / v_pool in (b,h,m,d) layout
// ---------------------------------------------------------------------------
__launch_bounds__(256)
__global__ void pool_split_k(const float* __restrict__ kvp, float* __restrict__ kpn,
                             float* __restrict__ vpl)
{
  const int bm = blockIdx.x;          // b*PL + m
  const int b = bm / PLn, m = bm % PLn;
  const int c = threadIdx.x;
  const int h = c >> 5, d = c & 31;
  float kval = kvp[(size_t)bm * 512 + c];
  float ss = kval * kval;
  #pragma unroll
  for (int mm = 16; mm >= 1; mm >>= 1) ss += __shfl_xor(ss, mm);
  const size_t oidx = (((size_t)b * NHn + h) * PLn + m) * HDn + d;
  kpn[oidx] = kval / fmaxf(sqrtf(ss), 1e-12f);
  vpl[oidx] = kvp[(size_t)bm * 512 + 256 + c];
}

// ---------------------------------------------------------------------------
// CPB MLP: tab[r][h] = relu(rct[r]@w1^T + b1) @ w2^T + b2   (2048 x 8)
// ---------------------------------------------------------------------------
__launch_bounds__(64)
__global__ void cpb_k(const float* __restrict__ rct, const float* __restrict__ w1,
                      const float* __restrict__ b1, const float* __restrict__ w2,
                      const float* __restrict__ b2, float* __restrict__ tab)
{
  const int r = blockIdx.x, t = threadIdx.x;
  const float c0 = rct[r*2], c1 = rct[r*2+1];
  float part[8] = {};
  #pragma unroll
  for (int jj = 0; jj < 8; ++jj) {
    const int j = t * 8 + jj;
    float hv = fmaxf(c0 * w1[j*2] + c1 * w1[j*2+1] + b1[j], 0.f);
    #pragma unroll
    for (int h = 0; h < 8; ++h) part[h] += hv * w2[h*512 + j];
  }
  #pragma unroll
  for (int h = 0; h < 8; ++h)
    for (int mm = 32; mm >= 1; mm >>= 1) part[h] += __shfl_xor(part[h], mm);
  if (t < 8) tab[r*8 + t] = part[t] + b2[t];
}

// ---------------------------------------------------------------------------
// Fused attention: one thread per (b,h,n); online softmax over 9 local + 196
// pool logits; k_pool/v_pool staged in LDS; local k/v gathered from kv buffer.
// ---------------------------------------------------------------------------
__launch_bounds__(256)
__global__ void attn_k(const float* __restrict__ qn_, const float* __restrict__ qs_,
                       const float* __restrict__ kv, const float* __restrict__ kpn,
                       const float* __restrict__ vpl, const float* __restrict__ tab,
                       const int* __restrict__ rpi, const float* __restrict__ rpb,
                       const float* __restrict__ lt, const float* __restrict__ lb,
                       float* __restrict__ outp)
{
  __shared__ __align__(16) float kp_s[PLn*HDn];
  __shared__ __align__(16) float vp_s[PLn*HDn];
  __shared__ float lt_s[HDn*LLn];
  __shared__ float lb_s[LLn], rpb_s[LLn];
  const int t = threadIdx.x;
  const int tile = blockIdx.x, h = blockIdx.y, b = blockIdx.z;
  {
    const float4* kp4 = (const float4*)(kpn + (size_t)(b*NHn + h) * PLn * HDn);
    const float4* vp4 = (const float4*)(vpl + (size_t)(b*NHn + h) * PLn * HDn);
    for (int i = t; i < PLn*HDn/4; i += 256) {
      ((float4*)kp_s)[i] = kp4[i];
      ((float4*)vp_s)[i] = vp4[i];
    }
    for (int i = t; i < HDn*LLn; i += 256) lt_s[i] = lt[h*HDn*LLn + i];
    if (t < LLn) { lb_s[t] = lb[h*LLn + t]; rpb_s[t] = rpb[h*LLn + t]; }
  }
  __syncthreads();
  const int n = tile * 256 + t;
  if (n >= Nn) return;
  const size_t rowq = ((size_t)b * Nn + n) * Cn + h * HDn;
  float qn[HDn], qs[HDn];
  #pragma unroll
  for (int dq = 0; dq < 8; ++dq) {
    float4 a  = ((const float4*)(qn_ + rowq))[dq];
    float4 s4 = ((const float4*)(qs_ + rowq))[dq];
    qn[dq*4]=a.x;  qn[dq*4+1]=a.y;  qn[dq*4+2]=a.z;  qn[dq*4+3]=a.w;
    qs[dq*4]=s4.x; qs[dq*4+1]=s4.y; qs[dq*4+2]=s4.z; qs[dq*4+3]=s4.w;
  }
  float m_run = -INFINITY, l_run = 0.f;
  float acc[HDn], ext[HDn];
  #pragma unroll
  for (int d = 0; d < HDn; ++d) { acc[d]=0.f; ext[d]=0.f; }
  const int pi = n / Wn, pj = n % Wn;
  #pragma unroll
  for (int l = 0; l < 9; ++l) {
    const int ii = pi + l/3 - 1, jj = pj + (l%3) - 1;
    if (ii < 0 || ii >= Hh || jj < 0 || jj >= Wn) continue;   // padding mask
    const int nb2 = ii * Wn + jj;
    const float* kr = kv + ((size_t)b * Nn + nb2) * 512 + h * HDn;
    float vv[HDn];
    float logit = rpb_s[l], e = lb_s[l];
    #pragma unroll
    for (int dq = 0; dq < 8; ++dq) {
      float4 kk = ((const float4*)kr)[dq];
      float4 v4 = ((const float4*)(kr + Cn))[dq];
      const int d = dq*4;
      vv[d]=v4.x; vv[d+1]=v4.y; vv[d+2]=v4.z; vv[d+3]=v4.w;
      logit += qs[d]*kk.x + qs[d+1]*kk.y + qs[d+2]*kk.z + qs[d+3]*kk.w;
      e += qn[d]*lt_s[d*LLn+l] + qn[d+1]*lt_s[(d+1)*LLn+l]
         + qn[d+2]*lt_s[(d+2)*LLn+l] + qn[d+3]*lt_s[(d+3)*LLn+l];
    }
    if (logit > m_run) {
      const float sc = expf(m_run - logit);
      l_run *= sc;
      #pragma unroll
      for (int d = 0; d < HDn; ++d) acc[d] *= sc;
      m_run = logit;
    }
    const float p = expf(logit - m_run);
    l_run += p;
    #pragma unroll
    for (int d = 0; d < HDn; ++d) { acc[d] += p * vv[d]; ext[d] += e * vv[d]; }
  }
  const int* rr = rpi + (size_t)n * PLn;
  for (int m = 0; m < PLn; ++m) {
    float logit = tab[(size_t)rr[m] * NHn + h];
    const float4* k4 = (const float4*)(kp_s + m * HDn);
    #pragma unroll
    for (int dq = 0; dq < 8; ++dq) {
      float4 kk = k4[dq];
      const int d = dq*4;
      logit += qs[d]*kk.x + qs[d+1]*kk.y + qs[d+2]*kk.z + qs[d+3]*kk.w;
    }
    if (logit > m_run) {
      const float sc = expf(m_run - logit);
      l_run *= sc;
      #pragma unroll
      for (int d = 0; d < HDn; ++d) acc[d] *= sc;
      m_run = logit;
    }
    const float p = expf(logit - m_run);
    l_run += p;
    const float4* v4p = (const float4*)(vp_s + m * HDn);
    #pragma unroll
    for (int dq = 0; dq < 8; ++dq) {
      float4 v4 = v4p[dq];
      const int d = dq*4;
      acc[d] += p*v4.x; acc[d+1] += p*v4.y; acc[d+2] += p*v4.z; acc[d+3] += p*v4.w;
    }
  }
  const float inv = 1.f / l_run;
  float* orow = outp + rowq;
  #pragma unroll
  for (int dq = 0; dq < 8; ++dq) {
    const int d = dq*4;
    float4 o;
    o.x = acc[d]*inv + ext[d];   o.y = acc[d+1]*inv + ext[d+1];
    o.z = acc[d+2]*inv + ext[d+2]; o.w = acc[d+3]*inv + ext[d+3];
    ((float4*)orow)[dq] = o;
  }
}

// ---------------------------------------------------------------------------
extern "C" void kernel_launch(void* const* d_in, const int* in_sizes, int n_in,
                              void* d_out, int out_size, void* d_ws, size_t ws_size,
                              hipStream_t stream)
{
  const float* x    = (const float*)d_in[0];
  const int*   rpi  = (const int*)d_in[3];
  const float* rct  = (const float*)d_in[4];
  const float* sls  = (const float*)d_in[5];
  // d_in[6] = padding_mask (recomputed in-kernel)
  const float* q_w  = (const float*)d_in[7];
  const float* q_b  = (const float*)d_in[8];
  const float* kv_w = (const float*)d_in[9];
  const float* kv_b = (const float*)d_in[10];
  const float* sr_w = (const float*)d_in[11];
  const float* sr_b = (const float*)d_in[12];
  const float* ng   = (const float*)d_in[13];
  const float* nbta = (const float*)d_in[14];
  const float* c1w  = (const float*)d_in[15];
  const float* c1b  = (const float*)d_in[16];
  const float* c2w  = (const float*)d_in[17];
  const float* c2b  = (const float*)d_in[18];
  const float* temp = (const float*)d_in[19];
  const float* qe   = (const float*)d_in[20];
  const float* rpb  = (const float*)d_in[21];
  const float* lt   = (const float*)d_in[22];
  const float* lb   = (const float*)d_in[23];
  const float* pw   = (const float*)d_in[24];
  const float* pb   = (const float*)d_in[25];

  const int M = Bn * Nn;                 // 12544
  float* ws  = (float*)d_ws;
  size_t o = 0;
  float* q    = ws + o;  o += (size_t)M * Cn;       // q raw -> q_norm (in place)
  float* qsb  = ws + o;  o += (size_t)M * Cn;       // q_scaled
  float* kvb  = ws + o;  o += (size_t)M * 2 * Cn;   // kv raw -> k normed in place, v untouched
  float* xsr  = ws + o;  o += (size_t)M * Cn;       // gelu(sr) ; reused as attn out
  float* pln  = ws + o;  o += (size_t)Bn * PLn * Cn;
  float* kvp  = ws + o;  o += (size_t)Bn * PLn * 2 * Cn;
  float* kpn  = ws + o;  o += (size_t)Bn * PLn * Cn;
  float* vpl  = ws + o;  o += (size_t)Bn * PLn * Cn;
  float* tab  = ws + o;  o += (size_t)KTABn * NHn;
  float* outp = xsr;                                 // xsr dead after pool_ln_k

  gemm_k<0><<<dim3(4, 196), 256, 0, stream>>>(x, q_w, q_b, q, M, 256, 256);
  gemm_k<0><<<dim3(8, 196), 256, 0, stream>>>(x, kv_w, kv_b, kvb, M, 512, 256);
  gemm_k<1><<<dim3(4, 196), 256, 0, stream>>>(x, sr_w, sr_b, xsr, M, 256, 256);
  norm_qk<<<M, 256, 0, stream>>>(q, qsb, kvb, sls, qe, temp);
  pool_ln_k<<<Bn*PLn, 256, 0, stream>>>(xsr, pln, ng, nbta);
  gemm_k<0><<<dim3(8, 13), 256, 0, stream>>>(pln, kv_w, kv_b, kvp, Bn*PLn, 512, 256);
  pool_split_k<<<Bn*PLn, 256, 0, stream>>>(kvp, kpn, vpl);
  cpb_k<<<KTABn, 64, 0, stream>>>(rct, c1w, c1b, c2w, c2b, tab);
  attn_k<<<dim3(13, NHn, Bn), 256, 0, stream>>>(q, qsb, kvb, kpn, vpl, tab, rpi, rpb, lt, lb, outp);
  gemm_k<0><<<dim3(4, 196), 256, 0, stream>>>(outp, pw, pb, (float*)d_out, M, 256, 256);
}

// Round 3
// 468.711 us; speedup vs baseline: 1.0553x; 1.0553x over previous
//
#include <hip/hip_runtime.h>
#include <hip/hip_bf16.h>
#include <math.h>

#define Bn   4
#define Hh   56
#define Wn   56
#define Cn   256
#define NHn  8
#define HDn  32
#define Nn   3136
#define LLn  9
#define PLn  196
#define PWn  14
#define KTABn 2048

// ---------------------------------------------------------------------------
// Generic tiled GEMM: C[M,Nc] = A[M,K] @ W[Nc,K]^T + bias ; EPI: 0=none 1=gelu
// ---------------------------------------------------------------------------
template <int EPI>
__launch_bounds__(256)
__global__ void gemm_k(const float* __restrict__ A, const float* __restrict__ W,
                       const float* __restrict__ bias, float* __restrict__ Co,
                       int Mr, int Nc, int K)
{
  __shared__ __align__(16) float As[16][64];
  __shared__ __align__(16) float Ws[16][64];
  const int t  = threadIdx.x;
  const int m0 = blockIdx.y * 64, n0 = blockIdx.x * 64;
  const int lm = t >> 2, lk = (t & 3) << 2;
  const int tx = t & 15, ty = t >> 4;
  float acc[4][4] = {};
  int arow = m0 + lm; if (arow >= Mr) arow = Mr - 1;
  const int wrow = n0 + lm;
  for (int k0 = 0; k0 < K; k0 += 16) {
    float4 av = *(const float4*)(A + (size_t)arow * K + k0 + lk);
    As[lk+0][lm] = av.x; As[lk+1][lm] = av.y; As[lk+2][lm] = av.z; As[lk+3][lm] = av.w;
    float4 wv = *(const float4*)(W + (size_t)wrow * K + k0 + lk);
    Ws[lk+0][lm] = wv.x; Ws[lk+1][lm] = wv.y; Ws[lk+2][lm] = wv.z; Ws[lk+3][lm] = wv.w;
    __syncthreads();
    #pragma unroll
    for (int k = 0; k < 16; ++k) {
      float4 a = *(const float4*)&As[k][ty << 2];
      float4 w = *(const float4*)&Ws[k][tx << 2];
      acc[0][0] += a.x*w.x; acc[0][1] += a.x*w.y; acc[0][2] += a.x*w.z; acc[0][3] += a.x*w.w;
      acc[1][0] += a.y*w.x; acc[1][1] += a.y*w.y; acc[1][2] += a.y*w.z; acc[1][3] += a.y*w.w;
      acc[2][0] += a.z*w.x; acc[2][1] += a.z*w.y; acc[2][2] += a.z*w.z; acc[2][3] += a.z*w.w;
      acc[3][0] += a.w*w.x; acc[3][1] += a.w*w.y; acc[3][2] += a.w*w.z; acc[3][3] += a.w*w.w;
    }
    __syncthreads();
  }
  #pragma unroll
  for (int i = 0; i < 4; ++i) {
    const int row = m0 + (ty << 2) + i;
    if (row >= Mr) continue;
    #pragma unroll
    for (int j = 0; j < 4; ++j) {
      const int col = n0 + (tx << 2) + j;
      float v = acc[i][j] + bias[col];
      if constexpr (EPI == 1) v = 0.5f * v * (1.0f + erff(v * 0.70710678118654752f));
      Co[(size_t)row * Nc + col] = v;
    }
  }
}

// ---------------------------------------------------------------------------
// Per-head L2 norm: q -> q_scaled (qn not stored); E2[b,h,l,n] = qn.lt + lb;
// k normed in place inside kv.
// ---------------------------------------------------------------------------
__launch_bounds__(256)
__global__ void norm_qk2(const float* __restrict__ q, float* __restrict__ qsb,
                         float* __restrict__ kv, float* __restrict__ E2,
                         const float* __restrict__ sls, const float* __restrict__ qe,
                         const float* __restrict__ temp, const float* __restrict__ lt,
                         const float* __restrict__ lb)
{
  const int row = blockIdx.x;            // b*Nn + n
  const int c = threadIdx.x;
  const int h = c >> 5, d = c & 31;
  const int b = row / Nn, n = row % Nn;
  float qv = q[(size_t)row * Cn + c];
  float ss = qv * qv;
  #pragma unroll
  for (int m = 16; m >= 1; m >>= 1) ss += __shfl_xor(ss, m);
  const float qn = qv / fmaxf(sqrtf(ss), 1e-12f);
  const float spt = log1pf(expf(temp[h]));
  qsb[(size_t)row * Cn + c] = (qn + qe[c]) * spt * sls[n];
  // E2: per (h,l) dot of qn with learnable_tokens column + learnable_bias
  #pragma unroll
  for (int l = 0; l < LLn; ++l) {
    float e = qn * lt[h * HDn * LLn + d * LLn + l];
    #pragma unroll
    for (int m = 16; m >= 1; m >>= 1) e += __shfl_xor(e, m);
    if (d == l) E2[(((size_t)(b * NHn + h)) * LLn + l) * Nn + n] = e + lb[h * LLn + l];
  }
  float kval = kv[(size_t)row * 512 + c];
  float ks = kval * kval;
  #pragma unroll
  for (int m = 16; m >= 1; m >>= 1) ks += __shfl_xor(ks, m);
  kv[(size_t)row * 512 + c] = kval / fmaxf(sqrtf(ks), 1e-12f);
}

// ---------------------------------------------------------------------------
// 4x4 average pool of x_sr (already gelu'd) + LayerNorm over C
// ---------------------------------------------------------------------------
__launch_bounds__(256)
__global__ void pool_ln_k(const float* __restrict__ xsr, float* __restrict__ pln,
                          const float* __restrict__ g, const float* __restrict__ bb)
{
  const int blk = blockIdx.x;
  const int b = blk / PLn, pc = blk % PLn;
  const int pi = pc / PWn, pj = pc % PWn;
  const int c = threadIdx.x;
  float s = 0.f;
  #pragma unroll
  for (int r = 0; r < 4; ++r)
    #pragma unroll
    for (int cc = 0; cc < 4; ++cc) {
      const int n = (pi*4 + r) * Wn + pj*4 + cc;
      s += xsr[((size_t)b * Nn + n) * Cn + c];
    }
  s *= (1.f/16.f);
  float sum = s, sq = s*s;
  #pragma unroll
  for (int m = 32; m >= 1; m >>= 1) { sum += __shfl_xor(sum, m); sq += __shfl_xor(sq, m); }
  __shared__ float sm[8];
  const int lane = c & 63, wid = c >> 6;
  if (lane == 0) { sm[wid] = sum; sm[4+wid] = sq; }
  __syncthreads();
  const float tot  = sm[0]+sm[1]+sm[2]+sm[3];
  const float totq = sm[4]+sm[5]+sm[6]+sm[7];
  const float mu  = tot * (1.f/256.f);
  const float var = totq * (1.f/256.f) - mu*mu;
  pln[(size_t)blk * Cn + c] = (s - mu) / sqrtf(var + 1e-5f) * g[c] + bb[c];
}

// ---------------------------------------------------------------------------
// split kvp -> k_pool (L2-normed per head) / v_pool in (b,h,m,d) layout
// ---------------------------------------------------------------------------
__launch_bounds__(256)
__global__ void pool_split_k(const float* __restrict__ kvp, float* __restrict__ kpn,
                             float* __restrict__ vpl)
{
  const int bm = blockIdx.x;          // b*PL + m
  const int b = bm / PLn, m = bm % PLn;
  const int c = threadIdx.x;
  const int h = c >> 5, d = c & 31;
  float kval = kvp[(size_t)bm * 512 + c];
  float ss = kval * kval;
  #pragma unroll
  for (int mm = 16; mm >= 1; mm >>= 1) ss += __shfl_xor(ss, mm);
  const size_t oidx = (((size_t)b * NHn + h) * PLn + m) * HDn + d;
  kpn[oidx] = kval / fmaxf(sqrtf(ss), 1e-12f);
  vpl[oidx] = kvp[(size_t)bm * 512 + 256 + c];
}

// ---------------------------------------------------------------------------
// CPB MLP: tab[r][h] = relu(rct[r]@w1^T + b1) @ w2^T + b2   (2048 x 8)
// ---------------------------------------------------------------------------
__launch_bounds__(64)
__global__ void cpb_k(const float* __restrict__ rct, const float* __restrict__ w1,
                      const float* __restrict__ b1, const float* __restrict__ w2,
                      const float* __restrict__ b2, float* __restrict__ tab)
{
  const int r = blockIdx.x, t = threadIdx.x;
  const float c0 = rct[r*2], c1 = rct[r*2+1];
  float part[8] = {};
  #pragma unroll
  for (int jj = 0; jj < 8; ++jj) {
    const int j = t * 8 + jj;
    float hv = fmaxf(c0 * w1[j*2] + c1 * w1[j*2+1] + b1[j], 0.f);
    #pragma unroll
    for (int h = 0; h < 8; ++h) part[h] += hv * w2[h*512 + j];
  }
  #pragma unroll
  for (int h = 0; h < 8; ++h)
    for (int mm = 32; mm >= 1; mm >>= 1) part[h] += __shfl_xor(part[h], mm);
  if (t < 8) tab[r*8 + t] = part[t] + b2[t];
}

// ---------------------------------------------------------------------------
// global max over tab (2048x8) and rpb (8x9) -> scal[0]  (for fixed-M softmax)
// ---------------------------------------------------------------------------
__launch_bounds__(256)
__global__ void redmax_k(const float* __restrict__ tab, const float* __restrict__ rpb,
                         float* __restrict__ scal)
{
  float mx = -1e30f;
  for (int i = threadIdx.x; i < KTABn*NHn; i += 256) mx = fmaxf(mx, tab[i]);
  if (threadIdx.x < NHn*LLn) mx = fmaxf(mx, rpb[threadIdx.x]);
  #pragma unroll
  for (int m = 32; m >= 1; m >>= 1) mx = fmaxf(mx, __shfl_xor(mx, m));
  __shared__ float sm[4];
  if ((threadIdx.x & 63) == 0) sm[threadIdx.x >> 6] = mx;
  __syncthreads();
  if (threadIdx.x == 0) scal[0] = fmaxf(fmaxf(sm[0], sm[1]), fmaxf(sm[2], sm[3]));
}

// ---------------------------------------------------------------------------
// Gather pool bias: bias2[h][m][n] = bf16(tab[rpi[n*PL+m]][h])  (coalesced in n)
// ---------------------------------------------------------------------------
__launch_bounds__(256)
__global__ void bias_g_k(const int* __restrict__ rpi, const float* __restrict__ tab,
                         __hip_bfloat16* __restrict__ bias2)
{
  const int tid = blockIdx.x * 256 + threadIdx.x;   // = m*Nn + n ; exact grid
  const int m = tid / Nn, n = tid % Nn;
  const int idx = rpi[(size_t)n * PLn + m];
  #pragma unroll
  for (int h = 0; h < NHn; ++h)
    bias2[((size_t)h * PLn + m) * Nn + n] = __float2bfloat16(tab[(size_t)idx * NHn + h]);
}

// ---------------------------------------------------------------------------
// Attention: 1 wave per block, 1 thread per (b,h,n). No LDS. Fixed-M softmax
// (M = ||qs|| + max bias, valid since all k are unit-norm). k_pool/v_pool read
// with wave-uniform addresses (scalarizable); bias2/E2 coalesced streams.
// ---------------------------------------------------------------------------
__launch_bounds__(64)
__global__ void attn3(const float* __restrict__ qs_, const float* __restrict__ E2,
                      const float* __restrict__ kv, const float* __restrict__ kpn,
                      const float* __restrict__ vpl, const __hip_bfloat16* __restrict__ bias2,
                      const float* __restrict__ rpb, const float* __restrict__ scal,
                      float* __restrict__ outp)
{
  const int t = threadIdx.x;
  const int tile = blockIdx.x, h = blockIdx.y, b = blockIdx.z;
  const int n = tile * 64 + t;                     // 49*64 == 3136, always valid
  const int bh = b * NHn + h;
  const size_t rowq = ((size_t)b * Nn + n) * Cn + h * HDn;

  float qs[HDn];
  #pragma unroll
  for (int dq = 0; dq < 8; ++dq) {
    float4 s4 = ((const float4*)(qs_ + rowq))[dq];
    qs[dq*4]=s4.x; qs[dq*4+1]=s4.y; qs[dq*4+2]=s4.z; qs[dq*4+3]=s4.w;
  }
  float s0=0,s1=0,s2=0,s3=0;
  #pragma unroll
  for (int dq = 0; dq < 8; ++dq) {
    s0 += qs[dq*4+0]*qs[dq*4+0]; s1 += qs[dq*4+1]*qs[dq*4+1];
    s2 += qs[dq*4+2]*qs[dq*4+2]; s3 += qs[dq*4+3]*qs[dq*4+3];
  }
  const float M = sqrtf((s0+s1)+(s2+s3)) + scal[0];

  const float* kbase = kpn + (size_t)bh * PLn * HDn;
  const float* vbase = vpl + (size_t)bh * PLn * HDn;
  const __hip_bfloat16* bptr = bias2 + (size_t)h * PLn * Nn + n;

  float l_run = 0.f;
  float acc[HDn];
  #pragma unroll
  for (int d = 0; d < HDn; ++d) acc[d] = 0.f;

  #pragma unroll 2
  for (int m = 0; m < PLn; ++m) {
    const float bias = __bfloat162float(bptr[(size_t)m * Nn]);
    const float4* k4 = (const float4*)(kbase + m * HDn);   // wave-uniform
    float p0=0,p1=0,p2=0,p3=0;
    #pragma unroll
    for (int dq = 0; dq < 8; ++dq) {
      float4 kk = k4[dq];
      p0 += qs[dq*4+0]*kk.x; p1 += qs[dq*4+1]*kk.y;
      p2 += qs[dq*4+2]*kk.z; p3 += qs[dq*4+3]*kk.w;
    }
    const float p = __expf(((p0+p1)+(p2+p3) + bias) - M);
    l_run += p;
    const float4* v4 = (const float4*)(vbase + m * HDn);   // wave-uniform
    #pragma unroll
    for (int dq = 0; dq < 8; ++dq) {
      float4 vv = v4[dq];
      const int d = dq*4;
      acc[d] += p*vv.x; acc[d+1] += p*vv.y; acc[d+2] += p*vv.z; acc[d+3] += p*vv.w;
    }
  }

  float ext[HDn];
  #pragma unroll
  for (int d = 0; d < HDn; ++d) ext[d] = 0.f;
  const int pi = n / Wn, pj = n % Wn;
  #pragma unroll
  for (int l = 0; l < LLn; ++l) {
    const int ii = pi + l/3 - 1, jj = pj + (l%3) - 1;
    if (ii < 0 || ii >= Hh || jj < 0 || jj >= Wn) continue;   // padding mask
    const int nb2 = ii * Wn + jj;
    const float e = E2[(((size_t)bh) * LLn + l) * Nn + n];
    const float* kr = kv + ((size_t)b * Nn + nb2) * 512 + h * HDn;
    float p0=0,p1=0,p2=0,p3=0;
    float vv[HDn];
    #pragma unroll
    for (int dq = 0; dq < 8; ++dq) {
      float4 kk = ((const float4*)kr)[dq];
      float4 v4 = ((const float4*)(kr + Cn))[dq];
      const int d = dq*4;
      vv[d]=v4.x; vv[d+1]=v4.y; vv[d+2]=v4.z; vv[d+3]=v4.w;
      p0 += qs[d]*kk.x; p1 += qs[d+1]*kk.y; p2 += qs[d+2]*kk.z; p3 += qs[d+3]*kk.w;
    }
    const float p = __expf(((p0+p1)+(p2+p3) + rpb[h*LLn + l]) - M);
    l_run += p;
    #pragma unroll
    for (int d = 0; d < HDn; ++d) { acc[d] += p * vv[d]; ext[d] += e * vv[d]; }
  }

  const float inv = 1.f / l_run;
  float* orow = outp + rowq;
  #pragma unroll
  for (int dq = 0; dq < 8; ++dq) {
    const int d = dq*4;
    float4 o;
    o.x = acc[d]*inv   + ext[d];   o.y = acc[d+1]*inv + ext[d+1];
    o.z = acc[d+2]*inv + ext[d+2]; o.w = acc[d+3]*inv + ext[d+3];
    ((float4*)orow)[dq] = o;
  }
}

// ---------------------------------------------------------------------------
extern "C" void kernel_launch(void* const* d_in, const int* in_sizes, int n_in,
                              void* d_out, int out_size, void* d_ws, size_t ws_size,
                              hipStream_t stream)
{
  const float* x    = (const float*)d_in[0];
  const int*   rpi  = (const int*)d_in[3];
  const float* rct  = (const float*)d_in[4];
  const float* sls  = (const float*)d_in[5];
  const float* q_w  = (const float*)d_in[7];
  const float* q_b  = (const float*)d_in[8];
  const float* kv_w = (const float*)d_in[9];
  const float* kv_b = (const float*)d_in[10];
  const float* sr_w = (const float*)d_in[11];
  const float* sr_b = (const float*)d_in[12];
  const float* ng   = (const float*)d_in[13];
  const float* nbta = (const float*)d_in[14];
  const float* c1w  = (const float*)d_in[15];
  const float* c1b  = (const float*)d_in[16];
  const float* c2w  = (const float*)d_in[17];
  const float* c2b  = (const float*)d_in[18];
  const float* temp = (const float*)d_in[19];
  const float* qe   = (const float*)d_in[20];
  const float* rpb  = (const float*)d_in[21];
  const float* lt   = (const float*)d_in[22];
  const float* lb   = (const float*)d_in[23];
  const float* pw   = (const float*)d_in[24];
  const float* pb   = (const float*)d_in[25];

  const int M = Bn * Nn;                 // 12544
  float* ws  = (float*)d_ws;
  size_t o = 0;
  float* qbuf = ws + o;  o += (size_t)M * Cn;       // raw q; dead after norm_qk2 -> reused for bias2
  float* qsb  = ws + o;  o += (size_t)M * Cn;       // q_scaled
  float* kvb  = ws + o;  o += (size_t)M * 2 * Cn;   // kv ; k normed in place
  float* xsr  = ws + o;  o += (size_t)M * Cn;       // gelu(sr); reused as attn out
  float* pln  = ws + o;  o += (size_t)Bn * PLn * Cn;
  float* kvp  = ws + o;  o += (size_t)Bn * PLn * 2 * Cn;
  float* kpn  = ws + o;  o += (size_t)Bn * PLn * Cn;
  float* vpl  = ws + o;  o += (size_t)Bn * PLn * Cn;
  float* tab  = ws + o;  o += (size_t)KTABn * NHn;
  float* scal = ws + o;  o += 8;
  float* E2   = ws + o;  o += (size_t)Bn * NHn * LLn * Nn;
  __hip_bfloat16* bias2 = (__hip_bfloat16*)qbuf;     // 9.83MB <= 12.85MB region
  float* outp = xsr;

  gemm_k<0><<<dim3(4, 196), 256, 0, stream>>>(x, q_w, q_b, qbuf, M, 256, 256);
  gemm_k<0><<<dim3(8, 196), 256, 0, stream>>>(x, kv_w, kv_b, kvb, M, 512, 256);
  gemm_k<1><<<dim3(4, 196), 256, 0, stream>>>(x, sr_w, sr_b, xsr, M, 256, 256);
  norm_qk2<<<M, 256, 0, stream>>>(qbuf, qsb, kvb, E2, sls, qe, temp, lt, lb);
  pool_ln_k<<<Bn*PLn, 256, 0, stream>>>(xsr, pln, ng, nbta);
  gemm_k<0><<<dim3(8, 13), 256, 0, stream>>>(pln, kv_w, kv_b, kvp, Bn*PLn, 512, 256);
  pool_split_k<<<Bn*PLn, 256, 0, stream>>>(kvp, kpn, vpl);
  cpb_k<<<KTABn, 64, 0, stream>>>(rct, c1w, c1b, c2w, c2b, tab);
  redmax_k<<<1, 256, 0, stream>>>(tab, rpb, scal);
  bias_g_k<<<(PLn*Nn)/256, 256, 0, stream>>>(rpi, tab, bias2);   // after norm_qk2 (qbuf dead)
  attn3<<<dim3(49, NHn, Bn), 64, 0, stream>>>(qsb, E2, kvb, kpn, vpl, bias2, rpb, scal, outp);
  gemm_k<0><<<dim3(4, 196), 256, 0, stream>>>(outp, pw, pb, (float*)d_out, M, 256, 256);
}

// Round 4
// 441.613 us; speedup vs baseline: 1.1201x; 1.0614x over previous
//
#include <hip/hip_runtime.h>
#include <hip/hip_bf16.h>
#include <math.h>

#define Bn   4
#define Hh   56
#define Wn   56
#define Cn   256
#define NHn  8
#define HDn  32
#define Nn   3136
#define LLn  9
#define PLn  196
#define PWn  14
#define KTABn 2048
#define Mrows 12544

// cvt5 segment offsets (elements)
#define XCNT   3211264            // 12544*256
#define QWOFF  XCNT               // +65536
#define KVWOFF (QWOFF + 65536)    // +131072
#define SRWOFF (KVWOFF + 131072)  // +65536
#define PWOFF  (SRWOFF + 65536)   // +65536
#define TOTCVT (PWOFF + 65536)    // 3538944

typedef __attribute__((ext_vector_type(8))) short short8v;
typedef __attribute__((ext_vector_type(4))) float float4v;

__device__ __forceinline__ unsigned short f2b(float f) {
  __hip_bfloat16 h = __float2bfloat16(f);
  return *(unsigned short*)&h;
}
__device__ __forceinline__ float b2f(unsigned short u) {
  union { unsigned int i; float f; } x; x.i = ((unsigned int)u) << 16; return x.f;
}

// ---------------------------------------------------------------------------
// Convert x + q_w + kv_w + sr_w + proj_w to one contiguous bf16 area.
// q|kv|sr weights become a single [1024 x 256] matrix for the fused QKVS GEMM.
// ---------------------------------------------------------------------------
__launch_bounds__(256)
__global__ void cvt5(const float* __restrict__ x, const float* __restrict__ qw,
                     const float* __restrict__ kvw, const float* __restrict__ srw,
                     const float* __restrict__ pw, unsigned short* __restrict__ dst)
{
  const int i = (blockIdx.x * 256 + threadIdx.x) * 4;   // grid exact: TOTCVT/1024 blocks
  const float* src; int off;
  if      (i < XCNT)   { src = x;   off = 0; }
  else if (i < KVWOFF) { src = qw;  off = QWOFF; }
  else if (i < SRWOFF) { src = kvw; off = KVWOFF; }
  else if (i < PWOFF)  { src = srw; off = SRWOFF; }
  else                 { src = pw;  off = PWOFF; }
  const float4 v = *(const float4*)(src + (i - off));
  ushort4 o2;
  o2.x = f2b(v.x); o2.y = f2b(v.y); o2.z = f2b(v.z); o2.w = f2b(v.w);
  *(ushort4*)(dst + i) = o2;
}

// ---------------------------------------------------------------------------
// bf16 MFMA GEMM: C[M,Nc] = A[M,256](bf16) @ W[Nc,256](bf16)^T + bias
// 128x128 block tile, 4 waves of 64x64, BK=64, XOR-swizzled LDS.
// MODE 0: bias=b0, plain.  MODE 1 (QKVS): seg bias (q|kv|sr) + gelu on seg 3.
// M must be /128, Nc /128, K=256 fixed.
// ---------------------------------------------------------------------------
template <int MODE>
__launch_bounds__(256)
__global__ void mgemm(const unsigned short* __restrict__ A,
                      const unsigned short* __restrict__ Wb,
                      const float* __restrict__ b0, const float* __restrict__ b1,
                      const float* __restrict__ b2, float* __restrict__ C, int Nc)
{
  __shared__ unsigned short As[128 * 64];
  __shared__ unsigned short Bs[128 * 64];
  const int t = threadIdx.x;
  const int w = t >> 6, lane = t & 63;
  const int q = lane >> 4, ln = lane & 15;
  const int n0 = blockIdx.x * 128, m0 = blockIdx.y * 128;
  const int wm = (w >> 1) * 64, wn = (w & 1) * 64;

  float4v acc[4][4];
  #pragma unroll
  for (int mt = 0; mt < 4; ++mt)
    #pragma unroll
    for (int nt = 0; nt < 4; ++nt)
      acc[mt][nt] = (float4v){0.f, 0.f, 0.f, 0.f};

  for (int k0 = 0; k0 < 256; k0 += 64) {
    #pragma unroll
    for (int j = 0; j < 4; ++j) {
      const int u = t + 256 * j;           // 0..1023 : (row, chunk-of-8-bf16)
      const int r = u >> 3, cg = u & 7;
      const int cs = cg ^ (r & 7);         // XOR swizzle slot
      const uint4 av = *(const uint4*)(A  + (size_t)(m0 + r) * 256 + k0 + cg * 8);
      *(uint4*)(As + r * 64 + cs * 8) = av;
      const uint4 bv = *(const uint4*)(Wb + (size_t)(n0 + r) * 256 + k0 + cg * 8);
      *(uint4*)(Bs + r * 64 + cs * 8) = bv;
    }
    __syncthreads();
    #pragma unroll
    for (int kk = 0; kk < 2; ++kk) {
      short8v af[4], bfr[4];
      const int cg = kk * 4 + q;
      #pragma unroll
      for (int mt = 0; mt < 4; ++mt) {
        const int r = wm + mt * 16 + ln;
        af[mt] = *(const short8v*)(As + r * 64 + (cg ^ (r & 7)) * 8);
      }
      #pragma unroll
      for (int nt = 0; nt < 4; ++nt) {
        const int r = wn + nt * 16 + ln;
        bfr[nt] = *(const short8v*)(Bs + r * 64 + (cg ^ (r & 7)) * 8);
      }
      #pragma unroll
      for (int mt = 0; mt < 4; ++mt)
        #pragma unroll
        for (int nt = 0; nt < 4; ++nt)
          acc[mt][nt] = __builtin_amdgcn_mfma_f32_16x16x32_bf16(af[mt], bfr[nt], acc[mt][nt], 0, 0, 0);
    }
    __syncthreads();
  }

  #pragma unroll
  for (int nt = 0; nt < 4; ++nt) {
    const int col = n0 + wn + nt * 16 + ln;
    float bias;
    if constexpr (MODE == 0) bias = b0[col];
    else {
      const int seg = col >> 8;
      bias = (seg == 0) ? b0[col] : (seg == 3 ? b2[col - 768] : b1[col - 256]);
    }
    #pragma unroll
    for (int mt = 0; mt < 4; ++mt) {
      #pragma unroll
      for (int r = 0; r < 4; ++r) {
        const int row = m0 + wm + mt * 16 + q * 4 + r;
        float v = acc[mt][nt][r] + bias;
        if constexpr (MODE == 1)
          if (col >= 768) v = 0.5f * v * (1.0f + erff(v * 0.70710678118654752f));
        C[(size_t)row * Nc + col] = v;
      }
    }
  }
}

// ---------------------------------------------------------------------------
// fp32 tiled GEMM (pool path only): C[M,Nc] = A[M,K] @ W[Nc,K]^T + bias
// ---------------------------------------------------------------------------
__launch_bounds__(256)
__global__ void gemm_k(const float* __restrict__ A, const float* __restrict__ W,
                       const float* __restrict__ bias, float* __restrict__ Co,
                       int Mr, int Nc, int K)
{
  __shared__ __align__(16) float As[16][64];
  __shared__ __align__(16) float Ws[16][64];
  const int t  = threadIdx.x;
  const int m0 = blockIdx.y * 64, n0 = blockIdx.x * 64;
  const int lm = t >> 2, lk = (t & 3) << 2;
  const int tx = t & 15, ty = t >> 4;
  float acc[4][4] = {};
  int arow = m0 + lm; if (arow >= Mr) arow = Mr - 1;
  const int wrow = n0 + lm;
  for (int k0 = 0; k0 < K; k0 += 16) {
    float4 av = *(const float4*)(A + (size_t)arow * K + k0 + lk);
    As[lk+0][lm] = av.x; As[lk+1][lm] = av.y; As[lk+2][lm] = av.z; As[lk+3][lm] = av.w;
    float4 wv = *(const float4*)(W + (size_t)wrow * K + k0 + lk);
    Ws[lk+0][lm] = wv.x; Ws[lk+1][lm] = wv.y; Ws[lk+2][lm] = wv.z; Ws[lk+3][lm] = wv.w;
    __syncthreads();
    #pragma unroll
    for (int k = 0; k < 16; ++k) {
      float4 a = *(const float4*)&As[k][ty << 2];
      float4 w = *(const float4*)&Ws[k][tx << 2];
      acc[0][0] += a.x*w.x; acc[0][1] += a.x*w.y; acc[0][2] += a.x*w.z; acc[0][3] += a.x*w.w;
      acc[1][0] += a.y*w.x; acc[1][1] += a.y*w.y; acc[1][2] += a.y*w.z; acc[1][3] += a.y*w.w;
      acc[2][0] += a.z*w.x; acc[2][1] += a.z*w.y; acc[2][2] += a.z*w.z; acc[2][3] += a.z*w.w;
      acc[3][0] += a.w*w.x; acc[3][1] += a.w*w.y; acc[3][2] += a.w*w.z; acc[3][3] += a.w*w.w;
    }
    __syncthreads();
  }
  #pragma unroll
  for (int i = 0; i < 4; ++i) {
    const int row = m0 + (ty << 2) + i;
    if (row >= Mr) continue;
    #pragma unroll
    for (int j = 0; j < 4; ++j) {
      const int col = n0 + (tx << 2) + j;
      Co[(size_t)row * Nc + col] = acc[i][j] + bias[col];
    }
  }
}

// ---------------------------------------------------------------------------
// Per-head L2 norm on fused [row][1024]: q (cols 0..255) -> q_scaled;
// E2[b,h,l,n] = qn.lt + lb ; k (cols 256..511) normed in place.
// ---------------------------------------------------------------------------
__launch_bounds__(256)
__global__ void norm_qk2(float* __restrict__ fused, float* __restrict__ qsb,
                         float* __restrict__ E2, const float* __restrict__ sls,
                         const float* __restrict__ qe, const float* __restrict__ temp,
                         const float* __restrict__ lt, const float* __restrict__ lb)
{
  const int row = blockIdx.x;            // b*Nn + n
  const int c = threadIdx.x;
  const int h = c >> 5, d = c & 31;
  const int b = row / Nn, n = row % Nn;
  float* f = fused + (size_t)row * 1024;
  float qv = f[c];
  float ss = qv * qv;
  #pragma unroll
  for (int m = 16; m >= 1; m >>= 1) ss += __shfl_xor(ss, m);
  const float qn = qv / fmaxf(sqrtf(ss), 1e-12f);
  const float spt = log1pf(expf(temp[h]));
  qsb[(size_t)row * Cn + c] = (qn + qe[c]) * spt * sls[n];
  #pragma unroll
  for (int ll = 0; ll < LLn; ++ll) {
    float e = qn * lt[h * HDn * LLn + d * LLn + ll];
    #pragma unroll
    for (int m = 16; m >= 1; m >>= 1) e += __shfl_xor(e, m);
    if (d == ll) E2[(((size_t)(b * NHn + h)) * LLn + ll) * Nn + n] = e + lb[h * LLn + ll];
  }
  float kval = f[256 + c];
  float ks = kval * kval;
  #pragma unroll
  for (int m = 16; m >= 1; m >>= 1) ks += __shfl_xor(ks, m);
  f[256 + c] = kval / fmaxf(sqrtf(ks), 1e-12f);
}

// ---------------------------------------------------------------------------
// 4x4 average pool of gelu'd sr (fused cols 768..1023) + LayerNorm over C
// ---------------------------------------------------------------------------
__launch_bounds__(256)
__global__ void pool_ln_k(const float* __restrict__ fused, float* __restrict__ pln,
                          const float* __restrict__ g, const float* __restrict__ bb)
{
  const int blk = blockIdx.x;
  const int b = blk / PLn, pc = blk % PLn;
  const int pi = pc / PWn, pj = pc % PWn;
  const int c = threadIdx.x;
  float s = 0.f;
  #pragma unroll
  for (int r = 0; r < 4; ++r)
    #pragma unroll
    for (int cc = 0; cc < 4; ++cc) {
      const int n = (pi*4 + r) * Wn + pj*4 + cc;
      s += fused[((size_t)b * Nn + n) * 1024 + 768 + c];
    }
  s *= (1.f/16.f);
  float sum = s, sq = s*s;
  #pragma unroll
  for (int m = 32; m >= 1; m >>= 1) { sum += __shfl_xor(sum, m); sq += __shfl_xor(sq, m); }
  __shared__ float sm[8];
  const int lane = c & 63, wid = c >> 6;
  if (lane == 0) { sm[wid] = sum; sm[4+wid] = sq; }
  __syncthreads();
  const float tot  = sm[0]+sm[1]+sm[2]+sm[3];
  const float totq = sm[4]+sm[5]+sm[6]+sm[7];
  const float mu  = tot * (1.f/256.f);
  const float var = totq * (1.f/256.f) - mu*mu;
  pln[(size_t)blk * Cn + c] = (s - mu) / sqrtf(var + 1e-5f) * g[c] + bb[c];
}

// ---------------------------------------------------------------------------
// split kvp -> k_pool (L2-normed per head) / v_pool in (b,h,m,d) layout
// ---------------------------------------------------------------------------
__launch_bounds__(256)
__global__ void pool_split_k(const float* __restrict__ kvp, float* __restrict__ kpn,
                             float* __restrict__ vpl)
{
  const int bm = blockIdx.x;
  const int b = bm / PLn, m = bm % PLn;
  const int c = threadIdx.x;
  const int h = c >> 5, d = c & 31;
  float kval = kvp[(size_t)bm * 512 + c];
  float ss = kval * kval;
  #pragma unroll
  for (int mm = 16; mm >= 1; mm >>= 1) ss += __shfl_xor(ss, mm);
  const size_t oidx = (((size_t)b * NHn + h) * PLn + m) * HDn + d;
  kpn[oidx] = kval / fmaxf(sqrtf(ss), 1e-12f);
  vpl[oidx] = kvp[(size_t)bm * 512 + 256 + c];
}

// ---------------------------------------------------------------------------
// CPB MLP: tab[r][h] = relu(rct[r]@w1^T + b1) @ w2^T + b2   (2048 x 8)
// ---------------------------------------------------------------------------
__launch_bounds__(64)
__global__ void cpb_k(const float* __restrict__ rct, const float* __restrict__ w1,
                      const float* __restrict__ b1, const float* __restrict__ w2,
                      const float* __restrict__ b2, float* __restrict__ tab)
{
  const int r = blockIdx.x, t = threadIdx.x;
  const float c0 = rct[r*2], c1 = rct[r*2+1];
  float part[8] = {};
  #pragma unroll
  for (int jj = 0; jj < 8; ++jj) {
    const int j = t * 8 + jj;
    float hv = fmaxf(c0 * w1[j*2] + c1 * w1[j*2+1] + b1[j], 0.f);
    #pragma unroll
    for (int h = 0; h < 8; ++h) part[h] += hv * w2[h*512 + j];
  }
  #pragma unroll
  for (int h = 0; h < 8; ++h)
    for (int mm = 32; mm >= 1; mm >>= 1) part[h] += __shfl_xor(part[h], mm);
  if (t < 8) tab[r*8 + t] = part[t] + b2[t];
}

// ---------------------------------------------------------------------------
// global max over tab and rpb -> scal[0]
// ---------------------------------------------------------------------------
__launch_bounds__(256)
__global__ void redmax_k(const float* __restrict__ tab, const float* __restrict__ rpb,
                         float* __restrict__ scal)
{
  float mx = -1e30f;
  for (int i = threadIdx.x; i < KTABn*NHn; i += 256) mx = fmaxf(mx, tab[i]);
  if (threadIdx.x < NHn*LLn) mx = fmaxf(mx, rpb[threadIdx.x]);
  #pragma unroll
  for (int m = 32; m >= 1; m >>= 1) mx = fmaxf(mx, __shfl_xor(mx, m));
  __shared__ float sm[4];
  if ((threadIdx.x & 63) == 0) sm[threadIdx.x >> 6] = mx;
  __syncthreads();
  if (threadIdx.x == 0) scal[0] = fmaxf(fmaxf(sm[0], sm[1]), fmaxf(sm[2], sm[3]));
}

// ---------------------------------------------------------------------------
// Gather pool bias: bias2[h][n][m] = bf16(tab[rpi[n*PL+m]][h])
// rpi read fully coalesced; writes coalesced per h-plane.
// ---------------------------------------------------------------------------
__launch_bounds__(256)
__global__ void bias_g_k(const int* __restrict__ rpi, const float* __restrict__ tab,
                         unsigned short* __restrict__ bias2)
{
  const int tid = blockIdx.x * 256 + threadIdx.x;   // n*PLn + m ; grid exact (2401 blocks)
  const int idx = rpi[tid];
  const int n = tid / PLn, m = tid - n * PLn;
  #pragma unroll
  for (int h = 0; h < NHn; ++h)
    bias2[((size_t)h * Nn + n) * PLn + m] = f2b(tab[(size_t)idx * NHn + h]);
}

// ---------------------------------------------------------------------------
// Sliced attention: wave = 16 n x 4 slices. Fixed-M softmax => partial sums
// are additive across slices; combine via shfl_xor(16/32). Output bf16.
// ---------------------------------------------------------------------------
__launch_bounds__(64)
__global__ void attn4(const float* __restrict__ qs_, const float* __restrict__ E2,
                      const float* __restrict__ fused, const float* __restrict__ kpn,
                      const float* __restrict__ vpl, const unsigned short* __restrict__ bias2,
                      const float* __restrict__ rpb, const float* __restrict__ scal,
                      unsigned short* __restrict__ outp)
{
  const int lane = threadIdx.x;
  const int tile = blockIdx.x, h = blockIdx.y, b = blockIdx.z;
  const int nl = lane & 15, s = lane >> 4;
  const int n = tile * 16 + nl;
  const int bh = b * NHn + h;
  const size_t rowq = ((size_t)b * Nn + n) * Cn + h * HDn;

  float qs[HDn];
  #pragma unroll
  for (int dq = 0; dq < 8; ++dq) {
    float4 s4 = ((const float4*)(qs_ + rowq))[dq];
    qs[dq*4]=s4.x; qs[dq*4+1]=s4.y; qs[dq*4+2]=s4.z; qs[dq*4+3]=s4.w;
  }
  float s0=0,s1=0,s2=0,s3=0;
  #pragma unroll
  for (int dq = 0; dq < 8; ++dq) {
    s0 += qs[dq*4+0]*qs[dq*4+0]; s1 += qs[dq*4+1]*qs[dq*4+1];
    s2 += qs[dq*4+2]*qs[dq*4+2]; s3 += qs[dq*4+3]*qs[dq*4+3];
  }
  const float M = sqrtf((s0+s1)+(s2+s3)) + scal[0];

  const float* kbase = kpn + (size_t)bh * PLn * HDn;
  const float* vbase = vpl + (size_t)bh * PLn * HDn;
  const unsigned short* bptr = bias2 + ((size_t)h * Nn + n) * PLn;

  float l_run = 0.f;
  float acc[HDn];
  #pragma unroll
  for (int d = 0; d < HDn; ++d) acc[d] = 0.f;

  const int mbase = s * 49;               // 4 slices x 49 = 196
  for (int i = 0; i < 49; ++i) {
    const int m = mbase + i;
    const float bias = b2f(bptr[m]);
    const float4* k4 = (const float4*)(kbase + m * HDn);
    float p0=0,p1=0,p2=0,p3=0;
    #pragma unroll
    for (int dq = 0; dq < 8; ++dq) {
      float4 kk = k4[dq];
      p0 += qs[dq*4+0]*kk.x; p1 += qs[dq*4+1]*kk.y;
      p2 += qs[dq*4+2]*kk.z; p3 += qs[dq*4+3]*kk.w;
    }
    const float p = __expf(((p0+p1)+(p2+p3) + bias) - M);
    l_run += p;
    const float4* v4 = (const float4*)(vbase + m * HDn);
    #pragma unroll
    for (int dq = 0; dq < 8; ++dq) {
      float4 vv = v4[dq];
      const int d = dq*4;
      acc[d] += p*vv.x; acc[d+1] += p*vv.y; acc[d+2] += p*vv.z; acc[d+3] += p*vv.w;
    }
  }

  float ext[HDn];
  #pragma unroll
  for (int d = 0; d < HDn; ++d) ext[d] = 0.f;
  const int pi = n / Wn, pj = n % Wn;
  for (int lc = s; lc < LLn; lc += 4) {
    const int ii = pi + lc/3 - 1, jj = pj + (lc%3) - 1;
    if (ii < 0 || ii >= Hh || jj < 0 || jj >= Wn) continue;
    const int nb2 = ii * Wn + jj;
    const float e = E2[((size_t)bh * LLn + lc) * Nn + n];
    const float* kr = fused + ((size_t)b * Nn + nb2) * 1024 + 256 + h * HDn;
    float p0=0,p1=0,p2=0,p3=0;
    float vv[HDn];
    #pragma unroll
    for (int dq = 0; dq < 8; ++dq) {
      float4 kk = ((const float4*)kr)[dq];
      float4 v4 = ((const float4*)(kr + Cn))[dq];
      const int d = dq*4;
      vv[d]=v4.x; vv[d+1]=v4.y; vv[d+2]=v4.z; vv[d+3]=v4.w;
      p0 += qs[d]*kk.x; p1 += qs[d+1]*kk.y; p2 += qs[d+2]*kk.z; p3 += qs[d+3]*kk.w;
    }
    const float p = __expf(((p0+p1)+(p2+p3) + rpb[h*LLn + lc]) - M);
    l_run += p;
    #pragma unroll
    for (int d = 0; d < HDn; ++d) { acc[d] += p * vv[d]; ext[d] += e * vv[d]; }
  }

  // combine the 4 slices (lanes 16 apart)
  l_run += __shfl_xor(l_run, 16); l_run += __shfl_xor(l_run, 32);
  #pragma unroll
  for (int d = 0; d < HDn; ++d) {
    acc[d] += __shfl_xor(acc[d], 16); acc[d] += __shfl_xor(acc[d], 32);
    ext[d] += __shfl_xor(ext[d], 16); ext[d] += __shfl_xor(ext[d], 32);
  }
  const float inv = 1.f / l_run;
  // slice s stores output elements [8s, 8s+8) as bf16 (16B per lane)
  uint4 u;
  {
    const int d0 = 8 * s;
    unsigned int w0 = f2b(acc[d0+0]*inv + ext[d0+0]) | ((unsigned int)f2b(acc[d0+1]*inv + ext[d0+1]) << 16);
    unsigned int w1 = f2b(acc[d0+2]*inv + ext[d0+2]) | ((unsigned int)f2b(acc[d0+3]*inv + ext[d0+3]) << 16);
    unsigned int w2 = f2b(acc[d0+4]*inv + ext[d0+4]) | ((unsigned int)f2b(acc[d0+5]*inv + ext[d0+5]) << 16);
    unsigned int w3 = f2b(acc[d0+6]*inv + ext[d0+6]) | ((unsigned int)f2b(acc[d0+7]*inv + ext[d0+7]) << 16);
    u.x = w0; u.y = w1; u.z = w2; u.w = w3;
  }
  ((uint4*)(outp + rowq))[s] = u;
}

// ---------------------------------------------------------------------------
extern "C" void kernel_launch(void* const* d_in, const int* in_sizes, int n_in,
                              void* d_out, int out_size, void* d_ws, size_t ws_size,
                              hipStream_t stream)
{
  const float* x    = (const float*)d_in[0];
  const int*   rpi  = (const int*)d_in[3];
  const float* rct  = (const float*)d_in[4];
  const float* sls  = (const float*)d_in[5];
  const float* q_w  = (const float*)d_in[7];
  const float* q_b  = (const float*)d_in[8];
  const float* kv_w = (const float*)d_in[9];
  const float* kv_b = (const float*)d_in[10];
  const float* sr_w = (const float*)d_in[11];
  const float* sr_b = (const float*)d_in[12];
  const float* ng   = (const float*)d_in[13];
  const float* nbta = (const float*)d_in[14];
  const float* c1w  = (const float*)d_in[15];
  const float* c1b  = (const float*)d_in[16];
  const float* c2w  = (const float*)d_in[17];
  const float* c2b  = (const float*)d_in[18];
  const float* temp = (const float*)d_in[19];
  const float* qe   = (const float*)d_in[20];
  const float* rpb  = (const float*)d_in[21];
  const float* lt   = (const float*)d_in[22];
  const float* lb   = (const float*)d_in[23];
  const float* pw   = (const float*)d_in[24];
  const float* pb   = (const float*)d_in[25];

  float* ws = (float*)d_ws;
  size_t o = 0;
  unsigned short* bf = (unsigned short*)(ws + o); o += TOTCVT / 2;      // bf16 area
  float* fused = ws + o;  o += (size_t)Mrows * 1024;                    // q|kv|sr outputs
  float* qsb   = ws + o;  o += (size_t)Mrows * Cn;
  float* E2    = ws + o;  o += (size_t)Bn * NHn * LLn * Nn;
  float* pln   = ws + o;  o += (size_t)Bn * PLn * Cn;
  float* kvp   = ws + o;  o += (size_t)Bn * PLn * 2 * Cn;
  float* kpn   = ws + o;  o += (size_t)Bn * PLn * Cn;
  float* vpl   = ws + o;  o += (size_t)Bn * PLn * Cn;
  float* tab   = ws + o;  o += (size_t)KTABn * NHn;
  float* scal  = ws + o;  o += 8;
  unsigned short* bias2 = (unsigned short*)(ws + o); o += (size_t)NHn * Nn * PLn / 2;
  unsigned short* outp  = (unsigned short*)(ws + o); o += (size_t)Mrows * Cn / 2;

  const unsigned short* xbf   = bf;
  const unsigned short* qkvsw = bf + QWOFF;   // [1024 x 256] = q_w | kv_w | sr_w
  const unsigned short* pwbf  = bf + PWOFF;

  cvt5<<<TOTCVT/1024, 256, 0, stream>>>(x, q_w, kv_w, sr_w, pw, bf);
  mgemm<1><<<dim3(8, 98), 256, 0, stream>>>(xbf, qkvsw, q_b, kv_b, sr_b, fused, 1024);
  norm_qk2<<<Mrows, 256, 0, stream>>>(fused, qsb, E2, sls, qe, temp, lt, lb);
  pool_ln_k<<<Bn*PLn, 256, 0, stream>>>(fused, pln, ng, nbta);
  gemm_k<<<dim3(8, 13), 256, 0, stream>>>(pln, kv_w, kv_b, kvp, Bn*PLn, 512, 256);
  pool_split_k<<<Bn*PLn, 256, 0, stream>>>(kvp, kpn, vpl);
  cpb_k<<<KTABn, 64, 0, stream>>>(rct, c1w, c1b, c2w, c2b, tab);
  redmax_k<<<1, 256, 0, stream>>>(tab, rpb, scal);
  bias_g_k<<<(Nn*PLn)/256, 256, 0, stream>>>(rpi, tab, bias2);
  attn4<<<dim3(Nn/16, NHn, Bn), 64, 0, stream>>>(qsb, E2, fused, kpn, vpl, bias2, rpb, scal, outp);
  mgemm<0><<<dim3(2, 98), 256, 0, stream>>>(outp, pwbf, pb, pb, pb, (float*)d_out, 256);
}